// Round 1
// baseline (541.436 us; speedup 1.0000x reference)
//
#include <hip/hip_runtime.h>

// GCN: 2x (GCNConv -> ReLU -> BatchNorm) -> Linear
// B=2, N=20000, E=640000, H=IN=128, OUT=10
//
// Pipeline per launch (all on `stream`, graph-capture safe):
//  1. histogram of dst -> cnt            (int atomics)
//  2. single-block scan -> rowstart, dinv = rsqrt(deg+1)
//  3. scatter edges into CSR (cursor = reused cnt buffer)
//  4. GEMM1: h = x @ W1
//  5. agg1: act = relu( sum_{e->n} norm*h[src] + dinv[n]^2*h[n] + b1 )  [gather-only, no atomics]
//  6. BN1 stats (col sum/sumsq) -> finalize (a,c affine)
//  7. GEMM2: h = (act*a1+c1) @ W2   [BN folded into A-load]
//  8. agg2 -> act
//  9. BN2 stats -> finalize
// 10. out = (act*a2+c2) @ Wc + bc

constexpr int Bb   = 2;
constexpr int Nn   = 20000;
constexpr int Ee   = 640000;
constexpr int Hh   = 128;
constexpr int OUTd = 10;
constexpr int Mm   = Bb * Nn;      // 40000 rows
#define EPSV 1e-5f

// ---------------- CSR build ----------------
__global__ __launch_bounds__(256) void hist_k(const int* __restrict__ dst, int* __restrict__ cnt) {
    int e = blockIdx.x * 256 + threadIdx.x;
    if (e < Ee) atomicAdd(&cnt[dst[e]], 1);
}

__global__ __launch_bounds__(1024) void scan_k(const int* __restrict__ cnt,
                                               int* __restrict__ rowstart,
                                               float* __restrict__ dinv) {
    __shared__ int sh[1024];
    int t = threadIdx.x;
    const int CH = (Nn + 1023) / 1024;  // 20
    int begin = t * CH;
    int end   = begin + CH; if (end > Nn) end = Nn;
    int s = 0;
    if (begin < Nn) for (int i = begin; i < end; i++) s += cnt[i];
    sh[t] = s;
    __syncthreads();
    for (int off = 1; off < 1024; off <<= 1) {
        int v = (t >= off) ? sh[t - off] : 0;
        __syncthreads();
        sh[t] += v;
        __syncthreads();
    }
    int run = sh[t] - s;  // exclusive prefix
    if (begin < Nn) {
        for (int i = begin; i < end; i++) {
            rowstart[i] = run;
            int c = cnt[i];
            run += c;
            dinv[i] = rsqrtf((float)c + 1.0f);  // +1 self-loop; deg>0 always
        }
        if (end == Nn) rowstart[Nn] = run;
    }
}

__global__ __launch_bounds__(256) void scatter_k(const int* __restrict__ src, const int* __restrict__ dst,
                                                 const int* __restrict__ rowstart, int* __restrict__ cursor,
                                                 int* __restrict__ csr) {
    int e = blockIdx.x * 256 + threadIdx.x;
    if (e < Ee) {
        int d = dst[e];
        int pos = rowstart[d] + atomicAdd(&cursor[d], 1);
        csr[pos] = src[e];
    }
}

// ---------------- GEMM (M x 128) @ (128 x 128), optional per-col affine on A ----------------
// block: 256 thr, 64 rows/block. Thread: cols 4*(t&31)..+3, rows (t>>5)*8..+7.
__global__ __launch_bounds__(256) void gemm128_k(const float* __restrict__ A,
                                                 const float* __restrict__ W,
                                                 float* __restrict__ C,
                                                 const float* __restrict__ affa,
                                                 const float* __restrict__ affc,
                                                 int use_aff) {
    __shared__ float Al[64 * 128];
    int t = threadIdx.x;
    int row0 = blockIdx.x * 64;

    const float4* A4  = (const float4*)(A + (size_t)row0 * 128);
    float4*       Al4 = (float4*)Al;
    if (use_aff) {
        #pragma unroll
        for (int i = 0; i < 8; i++) {
            int f  = t + i * 256;
            int c4 = f & 31;
            float4 v = A4[f];
            float4 a = ((const float4*)affa)[c4];
            float4 c = ((const float4*)affc)[c4];
            v.x = v.x * a.x + c.x;
            v.y = v.y * a.y + c.y;
            v.z = v.z * a.z + c.z;
            v.w = v.w * a.w + c.w;
            Al4[f] = v;
        }
    } else {
        #pragma unroll
        for (int i = 0; i < 8; i++) { int f = t + i * 256; Al4[f] = A4[f]; }
    }
    __syncthreads();

    int c4 = t & 31;
    int rb = t >> 5;  // 0..7
    float4 acc[8];
    #pragma unroll
    for (int i = 0; i < 8; i++) acc[i] = make_float4(0.f, 0.f, 0.f, 0.f);

    const float4* W4 = (const float4*)W;
    #pragma unroll 4
    for (int k = 0; k < 128; k++) {
        float4 w = W4[k * 32 + c4];  // coalesced row of W; L2-resident
        #pragma unroll
        for (int i = 0; i < 8; i++) {
            float a = Al[(rb * 8 + i) * 128 + k];  // broadcast read
            acc[i].x += a * w.x;
            acc[i].y += a * w.y;
            acc[i].z += a * w.z;
            acc[i].w += a * w.w;
        }
    }

    float4* C4 = (float4*)(C + (size_t)row0 * 128);
    #pragma unroll
    for (int i = 0; i < 8; i++) C4[(rb * 8 + i) * 32 + c4] = acc[i];
}

// ---------------- Aggregation: gather-only, fused self-loop + bias + ReLU ----------------
// block: 256 thr = 8 nodes x 32 float4-lanes. Both batches per thread.
__global__ __launch_bounds__(256) void agg_k(const float* __restrict__ h,
                                             const int* __restrict__ csr,
                                             const int* __restrict__ rowstart,
                                             const float* __restrict__ dinv,
                                             const float* __restrict__ bias,
                                             float* __restrict__ act) {
    int t  = threadIdx.x;
    int n  = blockIdx.x * 8 + (t >> 5);
    int f4 = t & 31;
    if (n >= Nn) return;

    const float4* h4 = (const float4*)h;
    float dn = dinv[n];
    float sl = dn * dn;

    float4 v0 = h4[(size_t)n * 32 + f4];
    float4 v1 = h4[(size_t)Nn * 32 + (size_t)n * 32 + f4];
    float4 acc0 = make_float4(v0.x * sl, v0.y * sl, v0.z * sl, v0.w * sl);
    float4 acc1 = make_float4(v1.x * sl, v1.y * sl, v1.z * sl, v1.w * sl);

    int beg = rowstart[n], end = rowstart[n + 1];
    for (int j = beg; j < end; j++) {
        int s   = csr[j];          // broadcast across 32 lanes
        float w = dinv[s] * dn;
        float4 a = h4[(size_t)s * 32 + f4];
        float4 b = h4[(size_t)Nn * 32 + (size_t)s * 32 + f4];
        acc0.x += w * a.x; acc0.y += w * a.y; acc0.z += w * a.z; acc0.w += w * a.w;
        acc1.x += w * b.x; acc1.y += w * b.y; acc1.z += w * b.z; acc1.w += w * b.w;
    }

    float4 bb = ((const float4*)bias)[f4];
    acc0.x = fmaxf(acc0.x + bb.x, 0.f);
    acc0.y = fmaxf(acc0.y + bb.y, 0.f);
    acc0.z = fmaxf(acc0.z + bb.z, 0.f);
    acc0.w = fmaxf(acc0.w + bb.w, 0.f);
    acc1.x = fmaxf(acc1.x + bb.x, 0.f);
    acc1.y = fmaxf(acc1.y + bb.y, 0.f);
    acc1.z = fmaxf(acc1.z + bb.z, 0.f);
    acc1.w = fmaxf(acc1.w + bb.w, 0.f);

    float4* o4 = (float4*)act;
    o4[(size_t)n * 32 + f4] = acc0;
    o4[(size_t)Nn * 32 + (size_t)n * 32 + f4] = acc1;
}

// ---------------- BatchNorm stats: per-column sum & sumsq ----------------
__global__ __launch_bounds__(256) void stats_k(const float* __restrict__ act, float* __restrict__ S) {
    int t    = threadIdx.x;
    int c    = t & 127;
    int half = t >> 7;
    float s = 0.f, ss = 0.f;
    for (int r = blockIdx.x * 2 + half; r < Mm; r += gridDim.x * 2) {
        float v = act[(size_t)r * 128 + c];
        s += v; ss += v * v;
    }
    __shared__ float sh[256];
    sh[t] = s;
    __syncthreads();
    if (half == 0) atomicAdd(&S[c], sh[t] + sh[t + 128]);
    __syncthreads();
    sh[t] = ss;
    __syncthreads();
    if (half == 0) atomicAdd(&S[128 + c], sh[t] + sh[t + 128]);
}

__global__ void finalize_k(const float* __restrict__ S, const float* __restrict__ g,
                           const float* __restrict__ bt, float* __restrict__ AF) {
    int c = threadIdx.x;  // 128
    const float invM = 1.0f / (float)Mm;
    float m   = S[c] * invM;
    float var = S[128 + c] * invM - m * m;
    float a   = g[c] * rsqrtf(var + EPSV);
    AF[c]       = a;
    AF[128 + c] = bt[c] - m * a;
}

// ---------------- Final GEMM: (M x 128) @ (128 x 10) + bc, with BN2 affine folded ----------------
__global__ __launch_bounds__(256) void gemmout_k(const float* __restrict__ act,
                                                 const float* __restrict__ Wc,
                                                 const float* __restrict__ bc,
                                                 const float* __restrict__ affa,
                                                 const float* __restrict__ affc,
                                                 float* __restrict__ out) {
    __shared__ float Wl[128 * OUTd];
    __shared__ float bl[OUTd];
    __shared__ float al[128], cl[128];
    int t = threadIdx.x;
    for (int i = t; i < 128 * OUTd; i += 256) Wl[i] = Wc[i];
    if (t < OUTd) bl[t] = bc[t];
    if (t < 128) { al[t] = affa[t]; cl[t] = affc[t]; }
    __syncthreads();

    int r = blockIdx.x * 256 + t;
    if (r >= Mm) return;

    float acc[OUTd];
    #pragma unroll
    for (int j = 0; j < OUTd; j++) acc[j] = 0.f;

    const float4* a4 = (const float4*)(act + (size_t)r * 128);
    #pragma unroll 4
    for (int k4 = 0; k4 < 32; k4++) {
        float4 v = a4[k4];
        int k = k4 * 4;
        float e0 = v.x * al[k + 0] + cl[k + 0];
        float e1 = v.y * al[k + 1] + cl[k + 1];
        float e2 = v.z * al[k + 2] + cl[k + 2];
        float e3 = v.w * al[k + 3] + cl[k + 3];
        #pragma unroll
        for (int j = 0; j < OUTd; j++) {
            acc[j] += e0 * Wl[(k + 0) * OUTd + j];
            acc[j] += e1 * Wl[(k + 1) * OUTd + j];
            acc[j] += e2 * Wl[(k + 2) * OUTd + j];
            acc[j] += e3 * Wl[(k + 3) * OUTd + j];
        }
    }
    #pragma unroll
    for (int j = 0; j < OUTd; j++) out[(size_t)r * OUTd + j] = acc[j] + bl[j];
}

extern "C" void kernel_launch(void* const* d_in, const int* in_sizes, int n_in,
                              void* d_out, int out_size, void* d_ws, size_t ws_size,
                              hipStream_t stream) {
    (void)in_sizes; (void)n_in; (void)out_size; (void)ws_size;

    const float* x   = (const float*)d_in[0];
    const float* W1  = (const float*)d_in[1];
    const float* b1  = (const float*)d_in[2];
    const float* W2  = (const float*)d_in[3];
    const float* b2  = (const float*)d_in[4];
    const float* g1  = (const float*)d_in[5];
    const float* bt1 = (const float*)d_in[6];
    const float* g2  = (const float*)d_in[7];
    const float* bt2 = (const float*)d_in[8];
    const float* Wc  = (const float*)d_in[9];
    const float* bc  = (const float*)d_in[10];
    const int*   ei  = (const int*)d_in[11];
    const int* srcp = ei;        // edge_index[0]
    const int* dstp = ei + Ee;   // edge_index[1]

    char* ws = (char*)d_ws;
    size_t off = 0;
    auto alloc = [&](size_t bytes) -> void* {
        void* p = ws + off;
        off += (bytes + 511) & ~(size_t)511;
        return p;
    };
    float* h     = (float*)alloc((size_t)Mm * Hh * 4);  // GEMM output buffer
    float* act   = (float*)alloc((size_t)Mm * Hh * 4);  // post-agg activations
    float* dinv  = (float*)alloc(Nn * 4);
    int*   cnt   = (int*)alloc(Nn * 4);                 // histogram, then cursor
    int*   rowst = (int*)alloc((Nn + 1) * 4);
    int*   csr   = (int*)alloc(Ee * 4);
    float* stats = (float*)alloc(512 * 4);              // S(128) SS(128) A(128) C(128)

    float* out = (float*)d_out;

    // CSR build + degree norm
    hipMemsetAsync(cnt, 0, Nn * 4, stream);
    hist_k<<<(Ee + 255) / 256, 256, 0, stream>>>(dstp, cnt);
    scan_k<<<1, 1024, 0, stream>>>(cnt, rowst, dinv);
    hipMemsetAsync(cnt, 0, Nn * 4, stream);
    scatter_k<<<(Ee + 255) / 256, 256, 0, stream>>>(srcp, dstp, rowst, cnt, csr);

    // Layer 1
    gemm128_k<<<Mm / 64, 256, 0, stream>>>(x, W1, h, nullptr, nullptr, 0);
    agg_k<<<(Nn + 7) / 8, 256, 0, stream>>>(h, csr, rowst, dinv, b1, act);
    hipMemsetAsync(stats, 0, 256 * 4, stream);
    stats_k<<<256, 256, 0, stream>>>(act, stats);
    finalize_k<<<1, 128, 0, stream>>>(stats, g1, bt1, stats + 256);

    // Layer 2 (BN1 affine folded into GEMM2's A-load)
    gemm128_k<<<Mm / 64, 256, 0, stream>>>(act, W2, h, stats + 256, stats + 384, 1);
    agg_k<<<(Nn + 7) / 8, 256, 0, stream>>>(h, csr, rowst, dinv, b2, act);
    hipMemsetAsync(stats, 0, 256 * 4, stream);
    stats_k<<<256, 256, 0, stream>>>(act, stats);
    finalize_k<<<1, 128, 0, stream>>>(stats, g2, bt2, stats + 256);

    // Classifier (BN2 affine folded)
    gemmout_k<<<(Mm + 255) / 256, 256, 0, stream>>>(act, Wc, bc, stats + 256, stats + 384, out);
}

// Round 2
// 383.662 us; speedup vs baseline: 1.4112x; 1.4112x over previous
//
#include <hip/hip_runtime.h>
#include <hip/hip_bf16.h>

// GCN: 2x (GCNConv -> ReLU -> BatchNorm) -> Linear
// B=2, N=20000, E=640000, H=IN=128, OUT=10
//
// Round-2 structure:
//  - h stored as bf16 interleaved (n, batch, 128): each edge gather = one 512B block
//  - GEMM1/GEMM2 use MFMA 16x16x32 bf16 (A read fp32 from global + cast, W staged
//    transposed bf16 in LDS), BN affine of previous layer folded into A-load
//  - agg: gather-only CSR, fused self-loop + bias + ReLU, fp32 accum, fp32 act out
//  - BN stats separate pass (memory cheap), affine folded downstream

constexpr int Nn   = 20000;
constexpr int Ee   = 640000;
constexpr int OUTd = 10;
constexpr int Mm   = 2 * Nn;  // 40000 rows
#define EPSV 1e-5f

using frag16 = __attribute__((ext_vector_type(8))) short;  // 8 bf16
using f32x4  = __attribute__((ext_vector_type(4))) float;

__device__ inline short bf(float f) {
    union { __hip_bfloat16 h; short s; } u;
    u.h = __float2bfloat16(f);
    return u.s;
}
__device__ inline float lo16(unsigned u) { union { unsigned v; float f; } x; x.v = u << 16;        return x.f; }
__device__ inline float hi16(unsigned u) { union { unsigned v; float f; } x; x.v = u & 0xffff0000u; return x.f; }

// ---------------- CSR build ----------------
__global__ __launch_bounds__(256) void hist_k(const int* __restrict__ dst, int* __restrict__ cnt) {
    int e = blockIdx.x * 256 + threadIdx.x;
    if (e < Ee) atomicAdd(&cnt[dst[e]], 1);
}

__global__ __launch_bounds__(1024) void scan_k(const int* __restrict__ cnt,
                                               int* __restrict__ rowstart,
                                               float* __restrict__ dinv) {
    __shared__ int sh[1024];
    int t = threadIdx.x;
    const int CH = (Nn + 1023) / 1024;  // 20
    int begin = t * CH;
    int end   = begin + CH; if (end > Nn) end = Nn;
    int s = 0;
    if (begin < Nn) for (int i = begin; i < end; i++) s += cnt[i];
    sh[t] = s;
    __syncthreads();
    for (int off = 1; off < 1024; off <<= 1) {
        int v = (t >= off) ? sh[t - off] : 0;
        __syncthreads();
        sh[t] += v;
        __syncthreads();
    }
    int run = sh[t] - s;  // exclusive prefix
    if (begin < Nn) {
        for (int i = begin; i < end; i++) {
            rowstart[i] = run;
            int c = cnt[i];
            run += c;
            dinv[i] = rsqrtf((float)c + 1.0f);  // +1 self-loop
        }
        if (end == Nn) rowstart[Nn] = run;
    }
}

__global__ __launch_bounds__(256) void scatter_k(const int* __restrict__ src, const int* __restrict__ dst,
                                                 const int* __restrict__ rowstart, int* __restrict__ cursor,
                                                 int* __restrict__ csr) {
    int e = blockIdx.x * 256 + threadIdx.x;
    if (e < Ee) {
        int d = dst[e];
        int pos = rowstart[d] + atomicAdd(&cursor[d], 1);
        csr[pos] = src[e];
    }
}

// ---------------- MFMA GEMM: (40000 x 128) @ (128 x 128) -> bf16 interleaved ----------------
// Block: 256 thr = 4 waves, 64 rows. Wave w: rows row0+16w .. +15, all 128 cols.
// Output layout: Hout[(n*2 + b)*128 + col] bf16, where global row = b*20000 + n.
__global__ __launch_bounds__(256) void gemm_mfma_k(const float* __restrict__ A,
                                                   const float* __restrict__ W,
                                                   unsigned short* __restrict__ Hout,
                                                   const float* __restrict__ affa,
                                                   const float* __restrict__ affc,
                                                   int use_aff) {
    __shared__ short Wl[128 * 136];  // Wl[n*136 + k], bf16, stride 272B (68 words, free 2-way)
    int t = threadIdx.x;

    // Stage W transposed as bf16: pack k-pairs -> conflict-free b32 LDS stores.
    for (int it = 0; it < 8; ++it) {
        int lin = it * 256 + t;       // 0..2047
        int kp  = lin & 63;           // k-pair index
        int n4  = (lin >> 6) * 4;     // 0,4,...,124
        float4 w0 = *(const float4*)(W + (size_t)(2 * kp) * 128 + n4);
        float4 w1 = *(const float4*)(W + (size_t)(2 * kp + 1) * 128 + n4);
        unsigned p0 = (unsigned)(unsigned short)bf(w0.x) | ((unsigned)(unsigned short)bf(w1.x) << 16);
        unsigned p1 = (unsigned)(unsigned short)bf(w0.y) | ((unsigned)(unsigned short)bf(w1.y) << 16);
        unsigned p2 = (unsigned)(unsigned short)bf(w0.z) | ((unsigned)(unsigned short)bf(w1.z) << 16);
        unsigned p3 = (unsigned)(unsigned short)bf(w0.w) | ((unsigned)(unsigned short)bf(w1.w) << 16);
        *(unsigned*)&Wl[(n4 + 0) * 136 + 2 * kp] = p0;
        *(unsigned*)&Wl[(n4 + 1) * 136 + 2 * kp] = p1;
        *(unsigned*)&Wl[(n4 + 2) * 136 + 2 * kp] = p2;
        *(unsigned*)&Wl[(n4 + 3) * 136 + 2 * kp] = p3;
    }
    __syncthreads();

    int wv = t >> 6, l = t & 63;
    int row_q = l >> 4;        // quad 0..3
    int lane16 = l & 15;
    int row0 = blockIdx.x * 64 + wv * 16;

    // A fragments: lane holds A[m][k0..k0+7], m = row0+lane16, k0 = 32q + row_q*8
    frag16 a[4];
    const float* Arow = A + (size_t)(row0 + lane16) * 128;
    #pragma unroll
    for (int q = 0; q < 4; ++q) {
        int k0 = q * 32 + row_q * 8;
        float4 v0 = *(const float4*)(Arow + k0);
        float4 v1 = *(const float4*)(Arow + k0 + 4);
        if (use_aff) {
            float4 a0 = *(const float4*)(affa + k0);
            float4 a1 = *(const float4*)(affa + k0 + 4);
            float4 c0 = *(const float4*)(affc + k0);
            float4 c1 = *(const float4*)(affc + k0 + 4);
            v0.x = v0.x * a0.x + c0.x; v0.y = v0.y * a0.y + c0.y;
            v0.z = v0.z * a0.z + c0.z; v0.w = v0.w * a0.w + c0.w;
            v1.x = v1.x * a1.x + c1.x; v1.y = v1.y * a1.y + c1.y;
            v1.z = v1.z * a1.z + c1.z; v1.w = v1.w * a1.w + c1.w;
        }
        frag16 fa = { bf(v0.x), bf(v0.y), bf(v0.z), bf(v0.w),
                      bf(v1.x), bf(v1.y), bf(v1.z), bf(v1.w) };
        a[q] = fa;
    }

    f32x4 acc[8];
    #pragma unroll
    for (int c = 0; c < 8; ++c) acc[c] = (f32x4){0.f, 0.f, 0.f, 0.f};

    #pragma unroll
    for (int c = 0; c < 8; ++c) {
        int n = c * 16 + lane16;
        #pragma unroll
        for (int q = 0; q < 4; ++q) {
            int k0 = q * 32 + row_q * 8;
            frag16 b = *(const frag16*)&Wl[n * 136 + k0];  // 16B-aligned (272*n+2*k0)
            acc[c] = __builtin_amdgcn_mfma_f32_16x16x32_bf16(a[q], b, acc[c], 0, 0, 0);
        }
    }

    // Store: D row = row0 + row_q*4 + r, col = c*16 + lane16, as bf16 interleaved.
    #pragma unroll
    for (int r = 0; r < 4; ++r) {
        int rg = row0 + row_q * 4 + r;
        int b  = rg >= Nn;
        int n  = rg - b * Nn;
        unsigned short* dst = Hout + (size_t)n * 256 + b * 128;
        #pragma unroll
        for (int c = 0; c < 8; ++c)
            dst[c * 16 + lane16] = (unsigned short)bf(acc[c][r]);
    }
}

// ---------------- Aggregation: gather-only over bf16 interleaved h ----------------
// Block: 256 thr = 8 nodes x 32 lanes. Lane l: batch l>>4, cols (l&15)*8 .. +7.
// One 16B load per edge per lane (512B/node contiguous).
__global__ __launch_bounds__(256) void agg_k(const unsigned short* __restrict__ h,
                                             const int* __restrict__ csr,
                                             const int* __restrict__ rowstart,
                                             const float* __restrict__ dinv,
                                             const float* __restrict__ bias,
                                             float* __restrict__ act) {
    int t = threadIdx.x;
    int n = blockIdx.x * 8 + (t >> 5);
    int l = t & 31;
    if (n >= Nn) return;

    const uint4* h4 = (const uint4*)h;  // 16B = 8 bf16; node n block = 32 uint4
    float dn = dinv[n];
    float sl = dn * dn;

    uint4 u = h4[(size_t)n * 32 + l];
    float acc[8];
    acc[0] = sl * lo16(u.x); acc[1] = sl * hi16(u.x);
    acc[2] = sl * lo16(u.y); acc[3] = sl * hi16(u.y);
    acc[4] = sl * lo16(u.z); acc[5] = sl * hi16(u.z);
    acc[6] = sl * lo16(u.w); acc[7] = sl * hi16(u.w);

    int beg = rowstart[n], end = rowstart[n + 1];
    int j = beg;
    for (; j + 1 < end; j += 2) {
        int s0 = csr[j], s1 = csr[j + 1];
        float w0 = dinv[s0] * dn, w1 = dinv[s1] * dn;
        uint4 v0 = h4[(size_t)s0 * 32 + l];
        uint4 v1 = h4[(size_t)s1 * 32 + l];
        acc[0] += w0 * lo16(v0.x); acc[1] += w0 * hi16(v0.x);
        acc[2] += w0 * lo16(v0.y); acc[3] += w0 * hi16(v0.y);
        acc[4] += w0 * lo16(v0.z); acc[5] += w0 * hi16(v0.z);
        acc[6] += w0 * lo16(v0.w); acc[7] += w0 * hi16(v0.w);
        acc[0] += w1 * lo16(v1.x); acc[1] += w1 * hi16(v1.x);
        acc[2] += w1 * lo16(v1.y); acc[3] += w1 * hi16(v1.y);
        acc[4] += w1 * lo16(v1.z); acc[5] += w1 * hi16(v1.z);
        acc[6] += w1 * lo16(v1.w); acc[7] += w1 * hi16(v1.w);
    }
    if (j < end) {
        int s0 = csr[j];
        float w0 = dinv[s0] * dn;
        uint4 v0 = h4[(size_t)s0 * 32 + l];
        acc[0] += w0 * lo16(v0.x); acc[1] += w0 * hi16(v0.x);
        acc[2] += w0 * lo16(v0.y); acc[3] += w0 * hi16(v0.y);
        acc[4] += w0 * lo16(v0.z); acc[5] += w0 * hi16(v0.z);
        acc[6] += w0 * lo16(v0.w); acc[7] += w0 * hi16(v0.w);
    }

    int cb = (l & 15) * 8;
    float4 b0 = *(const float4*)(bias + cb);
    float4 b1 = *(const float4*)(bias + cb + 4);
    float4 o0, o1;
    o0.x = fmaxf(acc[0] + b0.x, 0.f); o0.y = fmaxf(acc[1] + b0.y, 0.f);
    o0.z = fmaxf(acc[2] + b0.z, 0.f); o0.w = fmaxf(acc[3] + b0.w, 0.f);
    o1.x = fmaxf(acc[4] + b1.x, 0.f); o1.y = fmaxf(acc[5] + b1.y, 0.f);
    o1.z = fmaxf(acc[6] + b1.z, 0.f); o1.w = fmaxf(acc[7] + b1.w, 0.f);

    // act standard layout: row = batch*N + n
    float* orow = act + ((size_t)(l >> 4) * Nn + n) * 128 + cb;
    *(float4*)(orow)     = o0;
    *(float4*)(orow + 4) = o1;
}

// ---------------- BatchNorm stats: per-column sum & sumsq ----------------
__global__ __launch_bounds__(256) void stats_k(const float* __restrict__ act, float* __restrict__ S) {
    int t    = threadIdx.x;
    int c    = t & 127;
    int half = t >> 7;
    float s = 0.f, ss = 0.f;
    for (int r = blockIdx.x * 2 + half; r < Mm; r += gridDim.x * 2) {
        float v = act[(size_t)r * 128 + c];
        s += v; ss += v * v;
    }
    __shared__ float sh[256];
    sh[t] = s;
    __syncthreads();
    if (half == 0) atomicAdd(&S[c], sh[t] + sh[t + 128]);
    __syncthreads();
    sh[t] = ss;
    __syncthreads();
    if (half == 0) atomicAdd(&S[128 + c], sh[t] + sh[t + 128]);
}

__global__ void finalize_k(const float* __restrict__ S, const float* __restrict__ g,
                           const float* __restrict__ bt, float* __restrict__ AF) {
    int c = threadIdx.x;  // 128
    const float invM = 1.0f / (float)Mm;
    float m   = S[c] * invM;
    float var = S[128 + c] * invM - m * m;
    float a   = g[c] * rsqrtf(var + EPSV);
    AF[c]       = a;
    AF[128 + c] = bt[c] - m * a;
}

// ---------------- Final GEMM: (M x 128) @ (128 x 10) + bc, BN2 affine folded ----------------
__global__ __launch_bounds__(256) void gemmout_k(const float* __restrict__ act,
                                                 const float* __restrict__ Wc,
                                                 const float* __restrict__ bc,
                                                 const float* __restrict__ affa,
                                                 const float* __restrict__ affc,
                                                 float* __restrict__ out) {
    __shared__ float Wl[128 * OUTd];
    __shared__ float bl[OUTd];
    __shared__ float al[128], cl[128];
    int t = threadIdx.x;
    for (int i = t; i < 128 * OUTd; i += 256) Wl[i] = Wc[i];
    if (t < OUTd) bl[t] = bc[t];
    if (t < 128) { al[t] = affa[t]; cl[t] = affc[t]; }
    __syncthreads();

    int r = blockIdx.x * 256 + t;
    if (r >= Mm) return;

    float acc[OUTd];
    #pragma unroll
    for (int jj = 0; jj < OUTd; jj++) acc[jj] = 0.f;

    const float4* a4 = (const float4*)(act + (size_t)r * 128);
    #pragma unroll 4
    for (int k4 = 0; k4 < 32; k4++) {
        float4 v = a4[k4];
        int k = k4 * 4;
        float e0 = v.x * al[k + 0] + cl[k + 0];
        float e1 = v.y * al[k + 1] + cl[k + 1];
        float e2 = v.z * al[k + 2] + cl[k + 2];
        float e3 = v.w * al[k + 3] + cl[k + 3];
        #pragma unroll
        for (int jj = 0; jj < OUTd; jj++) {
            acc[jj] += e0 * Wl[(k + 0) * OUTd + jj];
            acc[jj] += e1 * Wl[(k + 1) * OUTd + jj];
            acc[jj] += e2 * Wl[(k + 2) * OUTd + jj];
            acc[jj] += e3 * Wl[(k + 3) * OUTd + jj];
        }
    }
    #pragma unroll
    for (int jj = 0; jj < OUTd; jj++) out[(size_t)r * OUTd + jj] = acc[jj] + bl[jj];
}

extern "C" void kernel_launch(void* const* d_in, const int* in_sizes, int n_in,
                              void* d_out, int out_size, void* d_ws, size_t ws_size,
                              hipStream_t stream) {
    (void)in_sizes; (void)n_in; (void)out_size; (void)ws_size;

    const float* x   = (const float*)d_in[0];
    const float* W1  = (const float*)d_in[1];
    const float* b1  = (const float*)d_in[2];
    const float* W2  = (const float*)d_in[3];
    const float* b2  = (const float*)d_in[4];
    const float* g1  = (const float*)d_in[5];
    const float* bt1 = (const float*)d_in[6];
    const float* g2  = (const float*)d_in[7];
    const float* bt2 = (const float*)d_in[8];
    const float* Wc  = (const float*)d_in[9];
    const float* bc  = (const float*)d_in[10];
    const int*   ei  = (const int*)d_in[11];
    const int* srcp = ei;        // edge_index[0]
    const int* dstp = ei + Ee;   // edge_index[1]

    char* ws = (char*)d_ws;
    size_t off = 0;
    auto alloc = [&](size_t bytes) -> void* {
        void* p = ws + off;
        off += (bytes + 511) & ~(size_t)511;
        return p;
    };
    unsigned short* h = (unsigned short*)alloc((size_t)Mm * 128 * 2);  // bf16 interleaved
    float* act   = (float*)alloc((size_t)Mm * 128 * 4);
    float* dinv  = (float*)alloc(Nn * 4);
    int*   cnt   = (int*)alloc(Nn * 4);
    int*   rowst = (int*)alloc((Nn + 1) * 4);
    int*   csr   = (int*)alloc(Ee * 4);
    float* stats = (float*)alloc(512 * 4);   // S(128) SS(128) | A(128) C(128)

    float* out = (float*)d_out;

    // CSR build + degree norm
    hipMemsetAsync(cnt, 0, Nn * 4, stream);
    hist_k<<<(Ee + 255) / 256, 256, 0, stream>>>(dstp, cnt);
    scan_k<<<1, 1024, 0, stream>>>(cnt, rowst, dinv);
    hipMemsetAsync(cnt, 0, Nn * 4, stream);
    scatter_k<<<(Ee + 255) / 256, 256, 0, stream>>>(srcp, dstp, rowst, cnt, csr);

    // Layer 1
    gemm_mfma_k<<<Mm / 64, 256, 0, stream>>>(x, W1, h, nullptr, nullptr, 0);
    agg_k<<<Nn / 8, 256, 0, stream>>>(h, csr, rowst, dinv, b1, act);
    hipMemsetAsync(stats, 0, 256 * 4, stream);
    stats_k<<<256, 256, 0, stream>>>(act, stats);
    finalize_k<<<1, 128, 0, stream>>>(stats, g1, bt1, stats + 256);

    // Layer 2 (BN1 affine folded into GEMM2 A-load)
    gemm_mfma_k<<<Mm / 64, 256, 0, stream>>>(act, W2, h, stats + 256, stats + 384, 1);
    agg_k<<<Nn / 8, 256, 0, stream>>>(h, csr, rowst, dinv, b2, act);
    hipMemsetAsync(stats, 0, 256 * 4, stream);
    stats_k<<<256, 256, 0, stream>>>(act, stats);
    finalize_k<<<1, 128, 0, stream>>>(stats, g2, bt2, stats + 256);

    // Classifier (BN2 affine folded)
    gemmout_k<<<(Mm + 255) / 256, 256, 0, stream>>>(act, Wc, bc, stats + 256, stats + 384, out);
}

// Round 3
// 304.792 us; speedup vs baseline: 1.7764x; 1.2588x over previous
//
#include <hip/hip_runtime.h>
#include <hip/hip_bf16.h>

// GCN: 2x (GCNConv -> ReLU -> BatchNorm) -> Linear
// B=2, N=20000, E=640000, H=IN=128, OUT=10
//
// Round-3 structure:
//  - ELL adjacency built in ONE scatter pass (atomic cursor == degree counter)
//  - h AND act stored bf16 interleaved (n, batch, 128): edge gather = one 512B block
//  - agg: 8/4/1-wide software-pipelined gathers (deep MLP), fused self-loop+bias+ReLU
//  - BN1 affine folded into W2 staging: (a.x+c)@W = x@(diag(a)W) + c@W
//    (c@W precomputed in finalize1, used as MFMA accumulator init)
//  - BN stats: atomic-free per-block partials, reduced in finalize (no memsets)
//  - 12 dispatches total

constexpr int Nn   = 20000;
constexpr int Ee   = 640000;
constexpr int OUTd = 10;
constexpr int Mm   = 2 * Nn;   // 40000 rows
constexpr int ELLW = 96;       // max degree slots; Poisson(32) => P(overflow) ~ 1e-14
#define EPSV 1e-5f

using frag16 = __attribute__((ext_vector_type(8))) short;  // 8 bf16
using f32x4  = __attribute__((ext_vector_type(4))) float;

__device__ inline short bf(float f) {
    union { __hip_bfloat16 h; short s; } u;
    u.h = __float2bfloat16(f);
    return u.s;
}
__device__ inline float lo16(unsigned u) { union { unsigned v; float f; } x; x.v = u << 16;        return x.f; }
__device__ inline float hi16(unsigned u) { union { unsigned v; float f; } x; x.v = u & 0xffff0000u; return x.f; }
__device__ inline float b2f(unsigned short s) { union { unsigned v; float f; } x; x.v = ((unsigned)s) << 16; return x.f; }
__device__ inline unsigned pack2(float f0, float f1) {
    return (unsigned)(unsigned short)bf(f0) | ((unsigned)(unsigned short)bf(f1) << 16);
}

// ---------------- adjacency: one-pass ELL scatter ----------------
__global__ __launch_bounds__(256) void scatter_ell_k(const int* __restrict__ src, const int* __restrict__ dst,
                                                     int* __restrict__ cnt, int* __restrict__ ell) {
    int e = blockIdx.x * 256 + threadIdx.x;
    if (e < Ee) {
        int d = dst[e];
        int pos = atomicAdd(&cnt[d], 1);
        if (pos < ELLW) ell[(size_t)d * ELLW + pos] = src[e];
    }
}

__global__ __launch_bounds__(256) void dinv_k(const int* __restrict__ cnt, float* __restrict__ dinv) {
    int n = blockIdx.x * 256 + threadIdx.x;
    if (n < Nn) dinv[n] = rsqrtf((float)cnt[n] + 1.0f);  // +1 self-loop
}

// ---------------- GEMM1: (40000 x 128 fp32) @ (128 x 128) -> bf16 interleaved ----------------
// Block: 256 thr = 4 waves, 64 rows. Output Hout[(n*2+b)*128 + col], row rg = b*Nn+n.
__global__ __launch_bounds__(256) void gemm1_k(const float* __restrict__ A,
                                               const float* __restrict__ W,
                                               unsigned short* __restrict__ Hout) {
    __shared__ short Wl[128 * 136];  // Wl[n*136 + k] bf16; stride 272B -> free 2-way
    int t = threadIdx.x;

    for (int it = 0; it < 8; ++it) {
        int lin = it * 256 + t;
        int kp  = lin & 63;
        int n4  = (lin >> 6) * 4;
        float4 w0 = *(const float4*)(W + (size_t)(2 * kp) * 128 + n4);
        float4 w1 = *(const float4*)(W + (size_t)(2 * kp + 1) * 128 + n4);
        *(unsigned*)&Wl[(n4 + 0) * 136 + 2 * kp] = pack2(w0.x, w1.x);
        *(unsigned*)&Wl[(n4 + 1) * 136 + 2 * kp] = pack2(w0.y, w1.y);
        *(unsigned*)&Wl[(n4 + 2) * 136 + 2 * kp] = pack2(w0.z, w1.z);
        *(unsigned*)&Wl[(n4 + 3) * 136 + 2 * kp] = pack2(w0.w, w1.w);
    }
    __syncthreads();

    int wv = t >> 6, l = t & 63;
    int row_q = l >> 4, lane16 = l & 15;
    int row0 = blockIdx.x * 64 + wv * 16;

    frag16 a[4];
    const float* Arow = A + (size_t)(row0 + lane16) * 128;
    #pragma unroll
    for (int q = 0; q < 4; ++q) {
        int k0 = q * 32 + row_q * 8;
        float4 v0 = *(const float4*)(Arow + k0);
        float4 v1 = *(const float4*)(Arow + k0 + 4);
        frag16 fa = { bf(v0.x), bf(v0.y), bf(v0.z), bf(v0.w),
                      bf(v1.x), bf(v1.y), bf(v1.z), bf(v1.w) };
        a[q] = fa;
    }

    f32x4 acc[8];
    #pragma unroll
    for (int c = 0; c < 8; ++c) acc[c] = (f32x4){0.f, 0.f, 0.f, 0.f};

    #pragma unroll
    for (int c = 0; c < 8; ++c) {
        int n = c * 16 + lane16;
        #pragma unroll
        for (int q = 0; q < 4; ++q) {
            int k0 = q * 32 + row_q * 8;
            frag16 b = *(const frag16*)&Wl[n * 136 + k0];
            acc[c] = __builtin_amdgcn_mfma_f32_16x16x32_bf16(a[q], b, acc[c], 0, 0, 0);
        }
    }

    #pragma unroll
    for (int r = 0; r < 4; ++r) {
        int rg = row0 + row_q * 4 + r;
        int b  = rg >= Nn;
        int n  = rg - b * Nn;
        unsigned short* dst = Hout + (size_t)n * 256 + b * 128;
        #pragma unroll
        for (int c = 0; c < 8; ++c)
            dst[c * 16 + lane16] = (unsigned short)bf(acc[c][r]);
    }
}

// ---------------- GEMM2: (bf16 interleaved act) @ (diag(a1)*W2) + d1 -> bf16 interleaved ----------------
// AF: [0..127]=a, [128..255]=c (unused here), [256..383]=d = c@W
__global__ __launch_bounds__(256) void gemm2_k(const unsigned short* __restrict__ Abf,
                                               const float* __restrict__ W,
                                               unsigned short* __restrict__ Hout,
                                               const float* __restrict__ AF) {
    __shared__ short Wl[128 * 136];
    int t = threadIdx.x;

    for (int it = 0; it < 8; ++it) {
        int lin = it * 256 + t;
        int kp  = lin & 63;
        int n4  = (lin >> 6) * 4;
        float a0 = AF[2 * kp], a1 = AF[2 * kp + 1];
        float4 w0 = *(const float4*)(W + (size_t)(2 * kp) * 128 + n4);
        float4 w1 = *(const float4*)(W + (size_t)(2 * kp + 1) * 128 + n4);
        w0.x *= a0; w0.y *= a0; w0.z *= a0; w0.w *= a0;
        w1.x *= a1; w1.y *= a1; w1.z *= a1; w1.w *= a1;
        *(unsigned*)&Wl[(n4 + 0) * 136 + 2 * kp] = pack2(w0.x, w1.x);
        *(unsigned*)&Wl[(n4 + 1) * 136 + 2 * kp] = pack2(w0.y, w1.y);
        *(unsigned*)&Wl[(n4 + 2) * 136 + 2 * kp] = pack2(w0.z, w1.z);
        *(unsigned*)&Wl[(n4 + 3) * 136 + 2 * kp] = pack2(w0.w, w1.w);
    }
    __syncthreads();

    int wv = t >> 6, l = t & 63;
    int row_q = l >> 4, lane16 = l & 15;
    int row0 = blockIdx.x * 64 + wv * 16;

    // A fragments: raw bf16 loads from interleaved layout
    int rgA = row0 + lane16;
    int bA  = rgA >= Nn;
    int nA  = rgA - bA * Nn;
    const unsigned short* Arow = Abf + (size_t)nA * 256 + bA * 128;
    frag16 a[4];
    #pragma unroll
    for (int q = 0; q < 4; ++q) {
        int k0 = q * 32 + row_q * 8;
        a[q] = *(const frag16*)(Arow + k0);
    }

    f32x4 acc[8];
    #pragma unroll
    for (int c = 0; c < 8; ++c) {
        float d = AF[256 + c * 16 + lane16];
        acc[c] = (f32x4){d, d, d, d};
    }

    #pragma unroll
    for (int c = 0; c < 8; ++c) {
        int n = c * 16 + lane16;
        #pragma unroll
        for (int q = 0; q < 4; ++q) {
            int k0 = q * 32 + row_q * 8;
            frag16 b = *(const frag16*)&Wl[n * 136 + k0];
            acc[c] = __builtin_amdgcn_mfma_f32_16x16x32_bf16(a[q], b, acc[c], 0, 0, 0);
        }
    }

    #pragma unroll
    for (int r = 0; r < 4; ++r) {
        int rg = row0 + row_q * 4 + r;
        int b  = rg >= Nn;
        int n  = rg - b * Nn;
        unsigned short* dst = Hout + (size_t)n * 256 + b * 128;
        #pragma unroll
        for (int c = 0; c < 8; ++c)
            dst[c * 16 + lane16] = (unsigned short)bf(acc[c][r]);
    }
}

// ---------------- Aggregation: gather-only over bf16 interleaved h, deep MLP ----------------
// Block: 256 thr = 8 nodes x 32 lanes. Lane l: batch l>>4, cols (l&15)*8..+7 (one 16B load/edge).
__device__ inline void accum8(const uint4& v, float w, float* acc) {
    acc[0] += w * lo16(v.x); acc[1] += w * hi16(v.x);
    acc[2] += w * lo16(v.y); acc[3] += w * hi16(v.y);
    acc[4] += w * lo16(v.z); acc[5] += w * hi16(v.z);
    acc[6] += w * lo16(v.w); acc[7] += w * hi16(v.w);
}

__global__ __launch_bounds__(256) void agg_k(const unsigned short* __restrict__ h,
                                             const int* __restrict__ ell,
                                             const int* __restrict__ cnt,
                                             const float* __restrict__ dinv,
                                             const float* __restrict__ bias,
                                             unsigned short* __restrict__ act) {
    int t = threadIdx.x;
    int n = blockIdx.x * 8 + (t >> 5);
    int l = t & 31;
    if (n >= Nn) return;

    const uint4* h4 = (const uint4*)h;
    float dn = dinv[n];
    float sl = dn * dn;

    uint4 u = h4[(size_t)n * 32 + l];
    float acc[8];
    acc[0] = sl * lo16(u.x); acc[1] = sl * hi16(u.x);
    acc[2] = sl * lo16(u.y); acc[3] = sl * hi16(u.y);
    acc[4] = sl * lo16(u.z); acc[5] = sl * hi16(u.z);
    acc[6] = sl * lo16(u.w); acc[7] = sl * hi16(u.w);

    int deg = cnt[n]; if (deg > ELLW) deg = ELLW;
    const int* row = ell + (size_t)n * ELLW;

    int j = 0;
    for (; j + 7 < deg; j += 8) {
        int s0 = row[j], s1 = row[j+1], s2 = row[j+2], s3 = row[j+3];
        int s4 = row[j+4], s5 = row[j+5], s6 = row[j+6], s7 = row[j+7];
        float w0 = dinv[s0] * dn, w1 = dinv[s1] * dn, w2 = dinv[s2] * dn, w3 = dinv[s3] * dn;
        float w4 = dinv[s4] * dn, w5 = dinv[s5] * dn, w6 = dinv[s6] * dn, w7 = dinv[s7] * dn;
        uint4 v0 = h4[(size_t)s0 * 32 + l];
        uint4 v1 = h4[(size_t)s1 * 32 + l];
        uint4 v2 = h4[(size_t)s2 * 32 + l];
        uint4 v3 = h4[(size_t)s3 * 32 + l];
        uint4 v4 = h4[(size_t)s4 * 32 + l];
        uint4 v5 = h4[(size_t)s5 * 32 + l];
        uint4 v6 = h4[(size_t)s6 * 32 + l];
        uint4 v7 = h4[(size_t)s7 * 32 + l];
        accum8(v0, w0, acc); accum8(v1, w1, acc); accum8(v2, w2, acc); accum8(v3, w3, acc);
        accum8(v4, w4, acc); accum8(v5, w5, acc); accum8(v6, w6, acc); accum8(v7, w7, acc);
    }
    for (; j + 3 < deg; j += 4) {
        int s0 = row[j], s1 = row[j+1], s2 = row[j+2], s3 = row[j+3];
        float w0 = dinv[s0] * dn, w1 = dinv[s1] * dn, w2 = dinv[s2] * dn, w3 = dinv[s3] * dn;
        uint4 v0 = h4[(size_t)s0 * 32 + l];
        uint4 v1 = h4[(size_t)s1 * 32 + l];
        uint4 v2 = h4[(size_t)s2 * 32 + l];
        uint4 v3 = h4[(size_t)s3 * 32 + l];
        accum8(v0, w0, acc); accum8(v1, w1, acc); accum8(v2, w2, acc); accum8(v3, w3, acc);
    }
    for (; j < deg; ++j) {
        int s0 = row[j];
        float w0 = dinv[s0] * dn;
        uint4 v0 = h4[(size_t)s0 * 32 + l];
        accum8(v0, w0, acc);
    }

    int cb = (l & 15) * 8;
    float4 b0 = *(const float4*)(bias + cb);
    float4 b1 = *(const float4*)(bias + cb + 4);
    float o0 = fmaxf(acc[0] + b0.x, 0.f), o1 = fmaxf(acc[1] + b0.y, 0.f);
    float o2 = fmaxf(acc[2] + b0.z, 0.f), o3 = fmaxf(acc[3] + b0.w, 0.f);
    float o4 = fmaxf(acc[4] + b1.x, 0.f), o5 = fmaxf(acc[5] + b1.y, 0.f);
    float o6 = fmaxf(acc[6] + b1.z, 0.f), o7 = fmaxf(acc[7] + b1.w, 0.f);

    uint4 st;
    st.x = pack2(o0, o1); st.y = pack2(o2, o3); st.z = pack2(o4, o5); st.w = pack2(o6, o7);
    int bsel = l >> 4;
    *(uint4*)(act + (size_t)n * 256 + bsel * 128 + cb) = st;
}

// ---------------- BN stats: per-block partial col sums (atomic-free) ----------------
__global__ __launch_bounds__(256) void stats_k(const unsigned short* __restrict__ act,
                                               float* __restrict__ P) {
    int t    = threadIdx.x;
    int c    = t & 127;
    int half = t >> 7;
    float s = 0.f, ss = 0.f;
    for (int r = blockIdx.x * 2 + half; r < Mm; r += 512) {
        float v = b2f(act[(size_t)r * 128 + c]);
        s += v; ss += v * v;
    }
    __shared__ float sh[256];
    sh[t] = s;
    __syncthreads();
    if (half == 0) P[blockIdx.x * 256 + c] = sh[t] + sh[t + 128];
    __syncthreads();
    sh[t] = ss;
    __syncthreads();
    if (half == 0) P[blockIdx.x * 256 + 128 + c] = sh[t] + sh[t + 128];
}

// ---------------- finalize: reduce partials -> affine (a,c); optionally d = c @ Wnext ----------------
__global__ __launch_bounds__(128) void finalize_k(const float* __restrict__ P,
                                                  const float* __restrict__ g,
                                                  const float* __restrict__ bt,
                                                  const float* __restrict__ Wnext,
                                                  float* __restrict__ AF,
                                                  int compute_d) {
    __shared__ float scc[128];
    int c = threadIdx.x;  // 128
    float s = 0.f, ss = 0.f;
    for (int b = 0; b < 256; ++b) {
        s  += P[b * 256 + c];
        ss += P[b * 256 + 128 + c];
    }
    const float invM = 1.0f / (float)Mm;
    float m   = s * invM;
    float var = ss * invM - m * m;
    float a   = g[c] * rsqrtf(var + EPSV);
    float cc  = bt[c] - m * a;
    AF[c]       = a;
    AF[128 + c] = cc;
    scc[c] = cc;
    __syncthreads();
    if (compute_d) {
        float d = 0.f;
        for (int k = 0; k < 128; ++k) d += scc[k] * Wnext[(size_t)k * 128 + c];
        AF[256 + c] = d;
    }
}

// ---------------- classifier: (bf16 act, affine in-register) @ Wc + bc -> fp32 out ----------------
__global__ __launch_bounds__(256) void gemmout_k(const unsigned short* __restrict__ act,
                                                 const float* __restrict__ Wc,
                                                 const float* __restrict__ bc,
                                                 const float* __restrict__ AF,
                                                 float* __restrict__ out) {
    __shared__ float Wl[128 * OUTd];
    __shared__ float bl[OUTd];
    __shared__ float al[128], cl[128];
    int t = threadIdx.x;
    for (int i = t; i < 128 * OUTd; i += 256) Wl[i] = Wc[i];
    if (t < OUTd) bl[t] = bc[t];
    if (t < 128) { al[t] = AF[t]; cl[t] = AF[128 + t]; }
    __syncthreads();

    int r = blockIdx.x * 256 + t;
    if (r >= Mm) return;
    int b = r >= Nn;
    int n = r - b * Nn;

    float acc[OUTd];
    #pragma unroll
    for (int jj = 0; jj < OUTd; jj++) acc[jj] = 0.f;

    const uint4* a4 = (const uint4*)(act + (size_t)n * 256 + b * 128);
    #pragma unroll 4
    for (int k4 = 0; k4 < 16; k4++) {
        uint4 u = a4[k4];
        int k = k4 * 8;
        float e0 = lo16(u.x) * al[k+0] + cl[k+0];
        float e1 = hi16(u.x) * al[k+1] + cl[k+1];
        float e2 = lo16(u.y) * al[k+2] + cl[k+2];
        float e3 = hi16(u.y) * al[k+3] + cl[k+3];
        float e4 = lo16(u.z) * al[k+4] + cl[k+4];
        float e5 = hi16(u.z) * al[k+5] + cl[k+5];
        float e6 = lo16(u.w) * al[k+6] + cl[k+6];
        float e7 = hi16(u.w) * al[k+7] + cl[k+7];
        #pragma unroll
        for (int jj = 0; jj < OUTd; jj++) {
            acc[jj] += e0 * Wl[(k+0) * OUTd + jj];
            acc[jj] += e1 * Wl[(k+1) * OUTd + jj];
            acc[jj] += e2 * Wl[(k+2) * OUTd + jj];
            acc[jj] += e3 * Wl[(k+3) * OUTd + jj];
            acc[jj] += e4 * Wl[(k+4) * OUTd + jj];
            acc[jj] += e5 * Wl[(k+5) * OUTd + jj];
            acc[jj] += e6 * Wl[(k+6) * OUTd + jj];
            acc[jj] += e7 * Wl[(k+7) * OUTd + jj];
        }
    }
    #pragma unroll
    for (int jj = 0; jj < OUTd; jj++) out[(size_t)r * OUTd + jj] = acc[jj] + bl[jj];
}

extern "C" void kernel_launch(void* const* d_in, const int* in_sizes, int n_in,
                              void* d_out, int out_size, void* d_ws, size_t ws_size,
                              hipStream_t stream) {
    (void)in_sizes; (void)n_in; (void)out_size; (void)ws_size;

    const float* x   = (const float*)d_in[0];
    const float* W1  = (const float*)d_in[1];
    const float* b1  = (const float*)d_in[2];
    const float* W2  = (const float*)d_in[3];
    const float* b2  = (const float*)d_in[4];
    const float* g1  = (const float*)d_in[5];
    const float* bt1 = (const float*)d_in[6];
    const float* g2  = (const float*)d_in[7];
    const float* bt2 = (const float*)d_in[8];
    const float* Wc  = (const float*)d_in[9];
    const float* bc  = (const float*)d_in[10];
    const int*   ei  = (const int*)d_in[11];
    const int* srcp = ei;        // edge_index[0]
    const int* dstp = ei + Ee;   // edge_index[1]

    char* ws = (char*)d_ws;
    size_t off = 0;
    auto alloc = [&](size_t bytes) -> void* {
        void* p = ws + off;
        off += (bytes + 511) & ~(size_t)511;
        return p;
    };
    unsigned short* h   = (unsigned short*)alloc((size_t)Mm * 128 * 2);  // bf16 interleaved
    unsigned short* act = (unsigned short*)alloc((size_t)Mm * 128 * 2);  // bf16 interleaved
    float* dinv = (float*)alloc(Nn * 4);
    int*   cnt  = (int*)alloc(Nn * 4);
    int*   ell  = (int*)alloc((size_t)Nn * ELLW * 4);
    float* P    = (float*)alloc(256 * 256 * 4);
    float* AF1  = (float*)alloc(512 * 4);  // a(128) c(128) d(128)
    float* AF2  = (float*)alloc(512 * 4);  // a(128) c(128)

    float* out = (float*)d_out;

    // adjacency (1 memset + 2 kernels)
    hipMemsetAsync(cnt, 0, Nn * 4, stream);
    scatter_ell_k<<<(Ee + 255) / 256, 256, 0, stream>>>(srcp, dstp, cnt, ell);
    dinv_k<<<(Nn + 255) / 256, 256, 0, stream>>>(cnt, dinv);

    // Layer 1
    gemm1_k<<<Mm / 64, 256, 0, stream>>>(x, W1, h);
    agg_k<<<Nn / 8, 256, 0, stream>>>(h, ell, cnt, dinv, b1, act);
    stats_k<<<256, 256, 0, stream>>>(act, P);
    finalize_k<<<1, 128, 0, stream>>>(P, g1, bt1, W2, AF1, 1);

    // Layer 2 (BN1 folded into W2 staging + d-init)
    gemm2_k<<<Mm / 64, 256, 0, stream>>>(act, W2, h, AF1);
    agg_k<<<Nn / 8, 256, 0, stream>>>(h, ell, cnt, dinv, b2, act);
    stats_k<<<256, 256, 0, stream>>>(act, P);
    finalize_k<<<1, 128, 0, stream>>>(P, g2, bt2, nullptr, AF2, 0);

    // Classifier (BN2 affine in-register)
    gemmout_k<<<(Mm + 255) / 256, 256, 0, stream>>>(act, Wc, bc, AF2, out);
}